// Round 17
// baseline (26.421 us; speedup 1.0000x reference)
//
#include <hip/hip_runtime.h>
#include <hip/hip_bf16.h>

#define IN_F 8192
#define OUT_F 8192
#define BATCH 64
#define KSPLIT 8

typedef __attribute__((ext_vector_type(8))) _Float16 f16x8_t;  // 8 f16 (4 VGPRs)
typedef __attribute__((ext_vector_type(2))) _Float16 f16x2_t;  // packed pair
typedef __attribute__((ext_vector_type(8))) ushort   u16x8_t;  // 16B store unit
typedef __attribute__((ext_vector_type(4))) float    f32x4_t;  // MFMA accumulator

// ---------------------------------------------------------------------------
// Fused stage-A: x fp32 -> f16 LDS (k-permuted) + f16-MFMA GEMM + partials.
// Grid: 32 N-tiles x 8 K-splits = 256 blocks x 512 thr (1 block/CU).
// R17 = R16 + TWO-DEEP q/sc/zw prefetch pipeline (3 rotating buffers):
// loads for group g+2 issue at the top of group g's compute, giving HBM
// ~2 group-times (~1800 cy/SIMD) to deliver instead of just-in-time.
// Dequant: int4->f16 magic (r=((q>>4i)&0x000F000F)|0x64006400; w=(r-c)*s),
// k-pair order [0,4,1,5,2,6,3,7] matched by the LDS x staging permutation.
// ---------------------------------------------------------------------------
__global__ void __launch_bounds__(512, 4)
wol_mfma(const float*  __restrict__ x,
         const int*    __restrict__ qw,
         const int*    __restrict__ qz,
         const float*  __restrict__ sc,
         ushort*       __restrict__ part) {
    const int nt   = blockIdx.x & 31;
    const int ks   = blockIdx.x >> 5;           // 0..7
    const int wid  = threadIdx.x >> 6;
    const int lane = threadIdx.x & 63;
    const int ln   = lane & 15;
    const int kb   = lane >> 4;                 // k-subblock 0..3
    const int colbase = nt * 256 + wid * 32;    // wave's 32 columns
    const int k0      = ks * 1024;              // block K range (8 groups)
    const int gbase   = k0 >> 7;
    const int qrowb   = k0 >> 3;                // 128 qrows per block

    // ---- prefetch groups 0 and 1 (in flight across LDS staging) ----
    unsigned qc[4][2];  float svc[2];  unsigned zwc[2];
    unsigned qn1[4][2]; float svn1[2]; unsigned zwn1[2];
#pragma unroll
    for (int kt = 0; kt < 4; ++kt)
#pragma unroll
        for (int nj = 0; nj < 2; ++nj)
            qc[kt][nj] = (unsigned)qw[(size_t)(qrowb + kt * 4 + kb) * OUT_F +
                                      colbase + nj * 16 + ln];
#pragma unroll
    for (int nj = 0; nj < 2; ++nj) {
        const int c = colbase + nj * 16 + ln;
        svc[nj] = sc[gbase * OUT_F + c];
        zwc[nj] = (unsigned)qz[gbase * (OUT_F / 8) + (c >> 3)];
    }
    __builtin_amdgcn_sched_barrier(0);
#pragma unroll
    for (int kt = 0; kt < 4; ++kt)
#pragma unroll
        for (int nj = 0; nj < 2; ++nj)
            qn1[kt][nj] = (unsigned)qw[(size_t)(qrowb + 16 + kt * 4 + kb) * OUT_F +
                                       colbase + nj * 16 + ln];
#pragma unroll
    for (int nj = 0; nj < 2; ++nj) {
        const int c = colbase + nj * 16 + ln;
        svn1[nj] = sc[(gbase + 1) * OUT_F + c];
        zwn1[nj] = (unsigned)qz[(gbase + 1) * (OUT_F / 8) + (c >> 3)];
    }
    __builtin_amdgcn_sched_barrier(0);          // pin both batches here

    // ---- fused staging: x fp32 -> f16, k-permuted, swizzled LDS (128KB) ----
    __shared__ ushort lds_x[128 * 64 * 8];
    {
        const int perm[8] = {0, 4, 1, 5, 2, 6, 3, 7};   // frag j -> source k
#pragma unroll
        for (int i = 0; i < 16; ++i) {
            const int idx = i * 512 + (int)threadIdx.x;  // 8192 frags
            const int row = idx >> 7;                    // 0..63
            const int k8l = idx & 127;                   // 0..127
            const float4* sp = (const float4*)&x[(size_t)row * IN_F + k0 + k8l * 8];
            const float4 a = sp[0], b = sp[1];
            const float f[8] = {a.x, a.y, a.z, a.w, b.x, b.y, b.z, b.w};
            union { ushort u[8]; u16x8_t v; } o;
#pragma unroll
            for (int j = 0; j < 8; ++j) {
                const _Float16 h = (_Float16)f[perm[j]];
                o.u[j] = *(const ushort*)&h;
            }
            unsigned byteoff = (unsigned)(row * 2048 + k8l * 16);
            byteoff ^= (unsigned)((row & 7) << 4);       // T2 XOR swizzle
            *(u16x8_t*)((char*)lds_x + byteoff) = o.v;
        }
    }
    __syncthreads();

    const unsigned xorv = (unsigned)((ln & 7) << 4);     // af-read swizzle

    f32x4_t acc[4][2];
#pragma unroll
    for (int mi = 0; mi < 4; ++mi)
#pragma unroll
        for (int nj = 0; nj < 2; ++nj) acc[mi][nj] = (f32x4_t)0.0f;

#pragma unroll 1
    for (int g = 0; g < 8; ++g) {               // 8 quant groups of 128 K
        // ---- issue prefetch for group g+2 (2-deep pipeline), pinned ----
        unsigned qn2[4][2]; float svn2[2]; unsigned zwn2[2];
        if (g < 6) {
            const int qrow2 = qrowb + (g + 2) * 16;
#pragma unroll
            for (int kt = 0; kt < 4; ++kt)
#pragma unroll
                for (int nj = 0; nj < 2; ++nj)
                    qn2[kt][nj] = (unsigned)qw[(size_t)(qrow2 + kt * 4 + kb) * OUT_F +
                                               colbase + nj * 16 + ln];
#pragma unroll
            for (int nj = 0; nj < 2; ++nj) {
                const int c = colbase + nj * 16 + ln;
                svn2[nj] = sc[(gbase + g + 2) * OUT_F + c];
                zwn2[nj] = (unsigned)qz[(gbase + g + 2) * (OUT_F / 8) + (c >> 3)];
            }
            __builtin_amdgcn_sched_barrier(0);  // loads stay ABOVE the compute
        }

        // per-group packed f16 constants: c2 = -(1024+zp) (exact), s2 = s
        f16x2_t c2[2], s2[2];
#pragma unroll
        for (int nj = 0; nj < 2; ++nj) {
            const unsigned zp = ((zwc[nj] >> ((ln & 7) * 4)) + 1u) & 15u;  // zp-1 stored
            const _Float16 hc = (_Float16)(-(float)(1024u + zp));
            const _Float16 hs = (_Float16)svc[nj];
            c2[nj][0] = hc; c2[nj][1] = hc;
            s2[nj][0] = hs; s2[nj][1] = hs;
        }

#pragma unroll
        for (int kt = 0; kt < 4; ++kt) {        // 4 K-steps of 32
            const unsigned kbyte = (unsigned)(g * 256 + kt * 64 + kb * 16) ^ xorv;
            f16x8_t af[4];
#pragma unroll
            for (int mi = 0; mi < 4; ++mi)
                af[mi] = *(const f16x8_t*)((const char*)lds_x +
                            (unsigned)((mi * 16 + ln) * 2048) + kbyte);
#pragma unroll
            for (int nj = 0; nj < 2; ++nj) {
                const unsigned qv = qc[kt][nj];
                // int4 -> f16 magic unpack: pairs (n_i, n_{i+4}) at +1024
                const unsigned r0 = ( qv        & 0x000F000Fu) | 0x64006400u;
                const unsigned r1 = ((qv >> 4)  & 0x000F000Fu) | 0x64006400u;
                const unsigned r2 = ((qv >> 8)  & 0x000F000Fu) | 0x64006400u;
                const unsigned r3 = ((qv >> 12) & 0x000F000Fu) | 0x64006400u;
                union { unsigned u[4]; f16x8_t v; } bu;
                union { unsigned u; f16x2_t h; } t0, t1, t2, t3;
                t0.u = r0; t1.u = r1; t2.u = r2; t3.u = r3;
                f16x2_t w0 = (t0.h + c2[nj]) * s2[nj];   // pk_add exact, pk_mul
                f16x2_t w1 = (t1.h + c2[nj]) * s2[nj];
                f16x2_t w2 = (t2.h + c2[nj]) * s2[nj];
                f16x2_t w3 = (t3.h + c2[nj]) * s2[nj];
                bu.u[0] = *(const unsigned*)&w0;
                bu.u[1] = *(const unsigned*)&w1;
                bu.u[2] = *(const unsigned*)&w2;
                bu.u[3] = *(const unsigned*)&w3;
#pragma unroll
                for (int mi = 0; mi < 4; ++mi)
                    acc[mi][nj] = __builtin_amdgcn_mfma_f32_16x16x32_f16(
                        af[mi], bu.v, acc[mi][nj], 0, 0, 0);
            }
        }

        // ---- rotate 3-buffer pipeline: qc <- qn1 <- qn2 ----
        if (g < 7) {
#pragma unroll
            for (int kt = 0; kt < 4; ++kt)
#pragma unroll
                for (int nj = 0; nj < 2; ++nj) qc[kt][nj] = qn1[kt][nj];
#pragma unroll
            for (int nj = 0; nj < 2; ++nj) { svc[nj] = svn1[nj]; zwc[nj] = zwn1[nj]; }
        }
        if (g < 6) {
#pragma unroll
            for (int kt = 0; kt < 4; ++kt)
#pragma unroll
                for (int nj = 0; nj < 2; ++nj) qn1[kt][nj] = qn2[kt][nj];
#pragma unroll
            for (int nj = 0; nj < 2; ++nj) { svn1[nj] = svn2[nj]; zwn1[nj] = zwn2[nj]; }
        }
    }

    // ---- epilogue: bf16 fragment-major partials, one 64B store/thread ----
    union { ushort u[32]; u16x8_t v8[4]; } ob;
#pragma unroll
    for (int mi = 0; mi < 4; ++mi)
#pragma unroll
        for (int nj = 0; nj < 2; ++nj)
#pragma unroll
            for (int j = 0; j < 4; ++j) {
                __hip_bfloat16 h = __float2bfloat16(acc[mi][nj][j]);
                ob.u[(mi * 2 + nj) * 4 + j] = *reinterpret_cast<ushort*>(&h);
            }
    u16x8_t* pb = (u16x8_t*)part + ((size_t)(ks * 32 + nt) * 512 + threadIdx.x) * 4;
#pragma unroll
    for (int i = 0; i < 4; ++i) pb[i] = ob.v8[i];
}

// ---------------------------------------------------------------------------
// Stage B: sum 8 bf16 K-split partials (fragment layout) + bias -> out.
// Each output element written exactly once. 65536 threads.
// ---------------------------------------------------------------------------
__global__ void __launch_bounds__(256)
wol_reduce(const ushort* __restrict__ part,
           const float*  __restrict__ bias,
           float* __restrict__ out) {
    const int u   = blockIdx.x * 256 + threadIdx.x;
    const int v8  = u & 3;               // which ushort8 of the thread's 32
    const int tid = (u >> 2) & 511;      // stage-A thread id
    const int nt  = u >> 11;             // stage-A N-tile

    float s[8];
#pragma unroll
    for (int e = 0; e < 8; ++e) s[e] = 0.0f;
#pragma unroll
    for (int ks = 0; ks < KSPLIT; ++ks) {
        const u16x8_t p = *((const u16x8_t*)part +
                            (((size_t)(ks * 32 + nt) * 512 + tid) * 4 + v8));
#pragma unroll
        for (int e = 0; e < 8; ++e) {
            union { unsigned b; float f; } cv;
            cv.b = ((unsigned)(ushort)p[e]) << 16;   // bf16 -> f32 exact
            s[e] += cv.f;
        }
    }

    const int wid = tid >> 6, lane = tid & 63;
    const int ln = lane & 15, kb = lane >> 4;
#pragma unroll
    for (int e = 0; e < 8; ++e) {
        const int idx = v8 * 8 + e;                  // (mi*2+nj)*4 + j
        const int mi = idx >> 3, nj = (idx >> 2) & 1, j = idx & 3;
        const int row = mi * 16 + kb * 4 + j;
        const int col = nt * 256 + wid * 32 + nj * 16 + ln;
        out[(size_t)row * OUT_F + col] = s[e] + bias[col];
    }
}

extern "C" void kernel_launch(void* const* d_in, const int* in_sizes, int n_in,
                              void* d_out, int out_size, void* d_ws, size_t ws_size,
                              hipStream_t stream) {
    const float* x    = (const float*)d_in[0];
    const int*   qw   = (const int*)d_in[1];
    const int*   qz   = (const int*)d_in[2];
    const float* sc   = (const float*)d_in[3];
    const float* bias = (const float*)d_in[4];
    float* out = (float*)d_out;

    ushort* prt = (ushort*)d_ws;                 // 8 MiB bf16 partials

    (void)in_sizes; (void)n_in; (void)ws_size; (void)out_size;

    wol_mfma<<<256, 512, 0, stream>>>(x, qw, qz, sc, prt);
    wol_reduce<<<256, 256, 0, stream>>>(prt, bias, out);
}